// Round 5
// baseline (555.075 us; speedup 1.0000x reference)
//
#include <hip/hip_runtime.h>

// TrendGRU R5: R4 structure + batched-reciprocal epilogue.
// Transcendentals dominated R4's issue (48 trans/wave-t at ~16 cyc each).
// Per r-row we now compute ONE rcp for the 4 sigmoid denominators
// (prefix/suffix-product trick) and ONE for the 2 tanh denominators:
// 48 -> 32 trans instrs per wave-t (+48 cheap v_mul).
// No clamps needed: |preact| <= 9.2 (r,z) / 18.3 (n) provably, so the
// 4-term product <= 2^37 -- no overflow.
// K=32 A-row layout: [0..23]=h(bf16) | 24=x_hi | 25=x_lo | 26=x_hi |
// 27=1.0 | 28=1.0 | 29..31=0.  B-frags carry Whi/Wlo + x/bias split terms,
// pre-scaled by log2(e) (r,z) and 2*log2(e) (n).
// Wave-private LDS round-trip (C-layout -> A-layout), no __syncthreads.

#define GRU_T 512
#define RS 40   // LDS row stride in shorts (80 B, 16B-aligned)

typedef __attribute__((ext_vector_type(8))) short bf16x8;
typedef __attribute__((ext_vector_type(4))) float f32x4;

__device__ __forceinline__ float bf16hi_f(float v) {   // RNE-to-bf16, as float
    unsigned u = __float_as_uint(v);
    u = (u + 0x7FFFu + ((u >> 16) & 1u)) & 0xFFFF0000u;
    return __uint_as_float(u);
}
__device__ __forceinline__ unsigned bf16_rne(float v) {
    unsigned u = __float_as_uint(v);
    return (u + 0x7FFFu + ((u >> 16) & 1u)) >> 16;
}
__device__ __forceinline__ f32x4 mfma16(bf16x8 a, bf16x8 b, f32x4 c) {
    return __builtin_amdgcn_mfma_f32_16x16x32_bf16(a, b, c, 0, 0, 0);
}

__global__ __launch_bounds__(256, 2) void trend_gru_mfma(
    const float* __restrict__ x,     // (B, T)
    const float* __restrict__ W_ih,  // (72,)
    const float* __restrict__ b_ih,  // (72,)
    const float* __restrict__ W_hh,  // (72, 24)
    const float* __restrict__ b_hh,  // (72,)
    const float* __restrict__ fc_w,  // (2, 24)
    const float* __restrict__ fc_b,  // (2,)
    float* __restrict__ out)         // (B, 2)
{
    const int lane = threadIdx.x & 63;
    const int wv   = threadIdx.x >> 6;
    const int n    = lane & 15;   // B col (output unit) / A row (element)
    const int quad = lane >> 4;

    __shared__ __align__(16) unsigned short S_all[4][16 * RS];
    unsigned short* S16 = &S_all[wv][0];
    const int elem0 = blockIdx.x * 64 + wv * 16;

    const float L2E = 1.4426950408889634f;

    // ---- build B fragments once (registers; wave-shared via MFMA) ----
    // B lane layout: col = lane&15, k = quad*8 + j.
    bf16x8 Bh[6], Bl[6], Bx[2];
#pragma unroll
    for (int tl = 0; tl < 6; ++tl) {
        const int g = tl >> 1;                  // 0=r, 1=z, 2=n_h
        const int jout = (tl & 1) * 16 + n;
        const bool valid = jout < 24;
        const float sc = (g == 2) ? 2.0f * L2E : L2E;
        const int R = (g < 2) ? g * 24 + jout : 48 + jout;
        const int Rc = valid ? R : 0;
        const float wx = (g < 2 && valid) ? sc * W_ih[Rc] : 0.0f;
        const float bb = valid ? sc * ((g < 2) ? (b_ih[Rc] + b_hh[Rc]) : b_hh[Rc]) : 0.0f;
        const float wxh = bf16hi_f(wx), bbh = bf16hi_f(bb);
        bf16x8 fh, fl;
#pragma unroll
        for (int j = 0; j < 8; ++j) {
            const int k = quad * 8 + j;
            float vh = 0.0f, vl = 0.0f;
            if (valid && k < 24) {
                const float w  = sc * W_hh[Rc * 24 + k];
                const float wh = bf16hi_f(w);
                vh = wh; vl = w - wh;
            } else if (valid) {
                if (k == 24 || k == 25) vh = wxh;          // Wih_hi * (x_hi, x_lo)
                else if (k == 26)       vh = wx - wxh;     // Wih_lo * x_hi
                else if (k == 27)       vh = bbh;          // b_hi * 1
                else if (k == 28)       vh = bb - bbh;     // b_lo * 1
            }
            fh[j] = (short)bf16_rne(vh);
            fl[j] = (short)bf16_rne(vl);
        }
        Bh[tl] = fh; Bl[tl] = fl;
    }
#pragma unroll
    for (int tl = 0; tl < 2; ++tl) {            // n_x tiles
        const int jout = tl * 16 + n;
        const bool valid = jout < 24;
        const int R = 48 + (valid ? jout : 0);
        const float sc = 2.0f * L2E;
        const float wx = valid ? sc * W_ih[R] : 0.0f;
        const float bb = valid ? sc * b_ih[R] : 0.0f;
        const float wxh = bf16hi_f(wx), bbh = bf16hi_f(bb);
        bf16x8 f;
#pragma unroll
        for (int j = 0; j < 8; ++j) {
            const int k = quad * 8 + j;
            float v = 0.0f;
            if (k == 24 || k == 25) v = wxh;
            else if (k == 26)       v = wx - wxh;
            else if (k == 27)       v = bbh;
            else if (k == 28)       v = bb - bbh;
            f[j] = (short)bf16_rne(v);
        }
        Bx[tl] = f;
    }

    // ---- init S rows: h=0, x slots 0, slots 27/28 = 1.0 bf16 ----
    if (lane < 16) {
        unsigned short* row = S16 + lane * RS;
        const int4 z4i = {0, 0, 0, 0};
        *(int4*)(row)      = z4i;
        *(int4*)(row + 8)  = z4i;
        *(int4*)(row + 16) = z4i;
        int4 c4;
        c4.x = 0;                               // slots 24,25 (x, staged per t)
        c4.y = 0x3F800000;                      // slot 26 (staged), 27 = 1.0
        c4.z = 0x00003F80;                      // slot 28 = 1.0, 29 = 0
        c4.w = 0;
        *(int4*)(row + 24) = c4;
    }

    // ---- per-lane FC weights ----
    const float fw00 = fc_w[n];
    const float fw01 = (n < 8) ? fc_w[16 + n] : 0.0f;
    const float fw10 = fc_w[24 + n];
    const float fw11 = (n < 8) ? fc_w[40 + n] : 0.0f;
    const float fcb0 = fc_b[0], fcb1 = fc_b[1];

    const float* xp = x + (size_t)(elem0 + n) * GRU_T;   // lanes<16 use it
    float xv = (lane < 16) ? xp[0] : 0.0f;

    float h0[4] = {0.f, 0.f, 0.f, 0.f};   // col j=n,    row m=quad*4+r
    float h1[4] = {0.f, 0.f, 0.f, 0.f};   // col j=16+n (valid n<8)

#pragma unroll 1
    for (int t = 0; t < GRU_T; ++t) {
        // stage x_t (lanes 0..15 own element row m=lane)
        if (lane < 16) {
            const float xh = bf16hi_f(xv);
            const unsigned xhi = __float_as_uint(xh) >> 16;
            const unsigned xlo = bf16_rne(xv - xh);
            *(unsigned*)(S16 + lane * RS + 24) = xhi | (xlo << 16);  // slots 24,25
            S16[lane * RS + 26] = (unsigned short)xhi;               // slot 26
        }
        const float xnext = (lane < 16) ? xp[(t + 1 < GRU_T) ? t + 1 : t] : 0.0f;

        // A fragment: row m = n, k = quad*8+j  (one b128)
        const bf16x8 A0 = *(const bf16x8*)(S16 + n * RS + quad * 8);

        const f32x4 z4 = {0.f, 0.f, 0.f, 0.f};
        f32x4 aR0 = mfma16(A0, Bh[0], z4); aR0 = mfma16(A0, Bl[0], aR0);
        f32x4 aR1 = mfma16(A0, Bh[1], z4); aR1 = mfma16(A0, Bl[1], aR1);
        f32x4 aZ0 = mfma16(A0, Bh[2], z4); aZ0 = mfma16(A0, Bl[2], aZ0);
        f32x4 aZ1 = mfma16(A0, Bh[3], z4); aZ1 = mfma16(A0, Bl[3], aZ1);
        f32x4 aN0 = mfma16(A0, Bh[4], z4); aN0 = mfma16(A0, Bl[4], aN0);
        f32x4 aN1 = mfma16(A0, Bh[5], z4); aN1 = mfma16(A0, Bl[5], aN1);
        const f32x4 aX0 = mfma16(A0, Bx[0], z4);
        const f32x4 aX1 = mfma16(A0, Bx[1], z4);

        // epilogue: batched-rcp gates + h update + bf16 writeback
#pragma unroll
        for (int r = 0; r < 4; ++r) {
            unsigned short* wrow = S16 + (quad * 4 + r) * RS;

            // 4 sigmoid denominators, ONE rcp (prefix/suffix products)
            const float eR0 = __builtin_amdgcn_exp2f(-aR0[r]);
            const float eZ0 = __builtin_amdgcn_exp2f(-aZ0[r]);
            const float eR1 = __builtin_amdgcn_exp2f(-aR1[r]);
            const float eZ1 = __builtin_amdgcn_exp2f(-aZ1[r]);
            const float A0d = 1.0f + eR0, B0d = 1.0f + eZ0;
            const float A1d = 1.0f + eR1, B1d = 1.0f + eZ1;
            const float P2 = A0d * B0d;
            const float P3 = P2 * A1d;
            const float P4 = P3 * B1d;
            const float inv  = __builtin_amdgcn_rcpf(P4);
            const float iB1  = inv * P3;          // z1
            const float iP3  = inv * B1d;
            const float iA1  = iP3 * P2;          // r1
            const float iP2  = iP3 * A1d;
            const float iB0  = iP2 * A0d;         // z0
            const float iA0  = iP2 * B0d;         // r0

            // 2 tanh denominators, ONE rcp
            const float np0 = fmaf(iA0, aN0[r], aX0[r]);
            const float np1 = fmaf(iA1, aN1[r], aX1[r]);
            const float eN0 = __builtin_amdgcn_exp2f(np0);
            const float eN1 = __builtin_amdgcn_exp2f(np1);
            const float C0d = 1.0f + eN0, C1d = 1.0f + eN1;
            const float invc = __builtin_amdgcn_rcpf(C0d * C1d);
            const float iC0 = invc * C1d;
            const float iC1 = invc * C0d;
            const float n0 = fmaf(-2.0f, iC0, 1.0f);
            const float n1 = fmaf(-2.0f, iC1, 1.0f);

            const float h0n = fmaf(iB0, h0[r] - n0, n0);
            const float h1n = fmaf(iB1, h1[r] - n1, n1);
            h0[r] = h0n;
            h1[r] = h1n;

            unsigned u0 = __float_as_uint(h0n);
            u0 += 0x7FFFu + ((u0 >> 16) & 1u);
            wrow[n] = (unsigned short)(u0 >> 16);          // ds_write_b16_d16_hi
            if (n < 8) {
                unsigned u1 = __float_as_uint(h1n);
                u1 += 0x7FFFu + ((u1 >> 16) & 1u);
                wrow[16 + n] = (unsigned short)(u1 >> 16);
            }
        }
        xv = xnext;
    }

    // ---- FC head: reduce over the 16 lanes of each quad ----
#pragma unroll
    for (int r = 0; r < 4; ++r) {
        float p0 = h0[r] * fw00 + ((n < 8) ? h1[r] * fw01 : 0.0f);
        float p1 = h0[r] * fw10 + ((n < 8) ? h1[r] * fw11 : 0.0f);
#pragma unroll
        for (int m = 1; m < 16; m <<= 1) {
            p0 += __shfl_xor(p0, m, 16);
            p1 += __shfl_xor(p1, m, 16);
        }
        if (n == 0) {
            const int e = elem0 + quad * 4 + r;
            float2 o; o.x = p0 + fcb0; o.y = p1 + fcb1;
            *(float2*)(out + (size_t)e * 2) = o;
        }
    }
}

extern "C" void kernel_launch(void* const* d_in, const int* in_sizes, int n_in,
                              void* d_out, int out_size, void* d_ws, size_t ws_size,
                              hipStream_t stream) {
    const float* x    = (const float*)d_in[0];
    const float* W_ih = (const float*)d_in[1];
    const float* b_ih = (const float*)d_in[2];
    const float* W_hh = (const float*)d_in[3];
    const float* b_hh = (const float*)d_in[4];
    const float* fc_w = (const float*)d_in[5];
    const float* fc_b = (const float*)d_in[6];
    float* out = (float*)d_out;

    const int B = in_sizes[0] / GRU_T;      // 32768
    const int grid = B / 64;                // 512 blocks x 256 threads (4 waves)
    trend_gru_mfma<<<grid, 256, 0, stream>>>(x, W_ih, b_ih, W_hh, b_hh,
                                             fc_w, fc_b, out);
}

// Round 7
// 476.419 us; speedup vs baseline: 1.1651x; 1.1651x over previous
//
#include <hip/hip_runtime.h>

// TrendGRU R7: R6 (32x32x16 MFMA, C = W*h orientation) with the v_perm
// selector fixed. __builtin_amdgcn_perm(a,b,sel): b = LOW dword (byte idx
// 0-3), a = HIGH dword (4-7). R6's 0x03020706 swapped each unit pair in the
// h writeback; 0x07060302 gives [bf16(s0) | bf16(s1)<<16].
// Structure: wave = 32 elements; A = weights (M=32 gate units, 24 valid),
// B = h (N=32 elements); one acc tile per gate; pad rows 24-31 are acc regs
// 12-15 (statically skipped). K-stream: [0..15]=h | [16..23]=h | 24=x_hi
// 25=x_lo 26=x_hi 27=1.0 28=1.0 | 29..31=0. W hi/lo split for fp32 recovery;
// r,z pre-scaled by log2(e), n by 2*log2(e); bias in k27/28; x_n-term as
// exact fp32 fma in the epilogue. 12 MFMA_32/wave-t, 2 ds_read_b128,
// 3 ds_write_b64. Wave-private LDS, 1 wave/block, no __syncthreads.

#define GRU_T 512
#define HS 40   // h LDS row stride in shorts (80 B: 16B-aligned, bank-spread)
#define FS 28   // FC LDS row stride in floats (16B-aligned float4 rows)

typedef __attribute__((ext_vector_type(8)))  short bf16x8;
typedef __attribute__((ext_vector_type(16))) float f32x16;

__device__ __forceinline__ float bf16hi_f(float v) {   // RNE-to-bf16, as float
    unsigned u = __float_as_uint(v);
    u = (u + 0x7FFFu + ((u >> 16) & 1u)) & 0xFFFF0000u;
    return __uint_as_float(u);
}
__device__ __forceinline__ unsigned bf16_rne(float v) {
    unsigned u = __float_as_uint(v);
    return (u + 0x7FFFu + ((u >> 16) & 1u)) >> 16;
}
// a pre-scaled by log2(e):  sigmoid = 1/(1+2^-a)
__device__ __forceinline__ float sigf(float a) {
    return __builtin_amdgcn_rcpf(1.0f + __builtin_amdgcn_exp2f(-a));
}
// v pre-scaled by 2*log2(e): tanh = 1 - 2/(2^v+1)
__device__ __forceinline__ float tnhf(float v) {
    return fmaf(-2.0f, __builtin_amdgcn_rcpf(1.0f + __builtin_amdgcn_exp2f(v)), 1.0f);
}
__device__ __forceinline__ f32x16 mfma32(bf16x8 a, bf16x8 b, f32x16 c) {
    return __builtin_amdgcn_mfma_f32_32x32x16_bf16(a, b, c, 0, 0, 0);
}

__global__ __launch_bounds__(64) void trend_gru_mfma32(
    const float* __restrict__ x,     // (B, T)
    const float* __restrict__ W_ih,  // (72,)
    const float* __restrict__ b_ih,  // (72,)
    const float* __restrict__ W_hh,  // (72, 24) rows r,z,n
    const float* __restrict__ b_hh,  // (72,)
    const float* __restrict__ fc_w,  // (2, 24)
    const float* __restrict__ fc_b,  // (2,)
    float* __restrict__ out)         // (B, 2)
{
    const int lane = threadIdx.x;
    const int e    = lane & 31;          // element (B-col / C-col)
    const int half = lane >> 5;
    const int elem0 = blockIdx.x * 32;

    __shared__ __align__(16) unsigned short Hlds[32 * HS];
    __shared__ __align__(16) float Flds[32 * FS];

    const float L2E = 1.4426950408889634f;

    // ---- A fragments (weights), built once: A[gate][kstep][hi/lo] ----
    // A layout: row m = lane&31, k = kstep*16 + (lane>>5)*8 + jj.
    bf16x8 A[3][2][2];
#pragma unroll
    for (int g = 0; g < 3; ++g) {
        const float sc = (g == 2) ? 2.0f * L2E : L2E;
        const int m = e;
        const bool valid = m < 24;
        const int R = g * 24 + (valid ? m : 0);
        const float wx = (g < 2 && valid) ? sc * W_ih[R] : 0.0f;
        const float bb = valid ? sc * ((g < 2) ? (b_ih[R] + b_hh[R]) : b_hh[R]) : 0.0f;
        const float wxh = bf16hi_f(wx), bbh = bf16hi_f(bb);
#pragma unroll
        for (int s = 0; s < 2; ++s) {
            bf16x8 fh, fl;
#pragma unroll
            for (int jj = 0; jj < 8; ++jj) {
                const int k = s * 16 + half * 8 + jj;
                float vh = 0.0f, vl = 0.0f;
                if (valid && k < 24) {
                    const float w  = sc * W_hh[R * 24 + k];
                    const float wh = bf16hi_f(w);
                    vh = wh; vl = w - wh;
                } else if (valid) {
                    if (k == 24 || k == 25)      vh = wxh;       // Wih_hi*(x_hi,x_lo)
                    else if (k == 26)            vh = wx - wxh;  // Wih_lo*x_hi
                    else if (k == 27)            vh = bbh;       // b_hi*1
                    else if (k == 28)            vh = bb - bbh;  // b_lo*1
                }
                fh[jj] = (short)bf16_rne(vh);
                fl[jj] = (short)bf16_rne(vl);
            }
            A[g][s][0] = fh;
            A[g][s][1] = fl;
        }
    }

    // ---- per-lane n-gate x-path constants (exact fp32) ----
    // slot s (0..11) -> unit j = (s&3) + 8*(s>>2) + 4*half  (C-layout rows)
    float wn_s[12], bn_s[12];
#pragma unroll
    for (int s = 0; s < 12; ++s) {
        const int j = (s & 3) + 8 * (s >> 2) + 4 * half;
        wn_s[s] = 2.0f * L2E * W_ih[48 + j];
        bn_s[s] = 2.0f * L2E * b_ih[48 + j];
    }

    // ---- zero-init h region (each lane zeroes its own writeback slots) ----
    {
        uint2 z2; z2.x = 0; z2.y = 0;
#pragma unroll
        for (int G = 0; G < 3; ++G)
            *(uint2*)(&Hlds[e * HS + G * 8 + half * 4]) = z2;
    }

    const float* xp = x + (size_t)(elem0 + e) * GRU_T;
    float xv = xp[0];

    float h[12];
#pragma unroll
    for (int s = 0; s < 12; ++s) h[s] = 0.0f;

    const f32x16 z16 = {0.f,0.f,0.f,0.f,0.f,0.f,0.f,0.f,
                        0.f,0.f,0.f,0.f,0.f,0.f,0.f,0.f};

#pragma unroll 1
    for (int t = 0; t < GRU_T; ++t) {
        // B step0: half0 -> h[e][0..7], half1 -> h[e][8..15]
        const bf16x8 B0 = *(const bf16x8*)(&Hlds[e * HS + half * 8]);
        // B step1: half0 -> h[e][16..23]; half1 -> in-register x pack (k24..31)
        bf16x8 B1 = *(const bf16x8*)(&Hlds[e * HS + 16]);
        {
            const unsigned uhi = bf16_rne(xv);
            const float xh = __uint_as_float(uhi << 16);
            const unsigned ulo = bf16_rne(xv - xh);
            uint4 xq;
            xq.x = uhi | (ulo << 16);        // k24=x_hi, k25=x_lo
            xq.y = uhi | 0x3F800000u;        // k26=x_hi, k27=1.0
            xq.z = 0x00003F80u;              // k28=1.0,  k29=0
            xq.w = 0;                        // k30,k31=0
            if (half) B1 = *(bf16x8*)&xq;
        }
        const float xnext = xp[(t + 1 < GRU_T) ? t + 1 : t];

        f32x16 aR = mfma32(A[0][0][0], B0, z16);
        aR = mfma32(A[0][0][1], B0, aR);
        aR = mfma32(A[0][1][0], B1, aR);
        aR = mfma32(A[0][1][1], B1, aR);
        f32x16 aZ = mfma32(A[1][0][0], B0, z16);
        aZ = mfma32(A[1][0][1], B0, aZ);
        aZ = mfma32(A[1][1][0], B1, aZ);
        aZ = mfma32(A[1][1][1], B1, aZ);
        f32x16 aN = mfma32(A[2][0][0], B0, z16);
        aN = mfma32(A[2][0][1], B0, aN);
        aN = mfma32(A[2][1][0], B1, aN);
        aN = mfma32(A[2][1][1], B1, aN);

        // epilogue: regs 0..11 only (12..15 are pad rows 24..31, skipped)
#pragma unroll
        for (int G = 0; G < 3; ++G) {
            unsigned u4[4];
#pragma unroll
            for (int q = 0; q < 4; ++q) {
                const int s = G * 4 + q;
                const float rr  = sigf(aR[s]);
                const float zz  = sigf(aZ[s]);
                const float aXv = fmaf(wn_s[s], xv, bn_s[s]);
                const float nn  = tnhf(fmaf(rr, aN[s], aXv));
                const float hn  = fmaf(zz, h[s] - nn, nn);
                h[s] = hn;
                unsigned u = __float_as_uint(hn);
                u4[q] = u + 0x7FFFu + ((u >> 16) & 1u);
            }
            // perm(a=HIGH dword, b=LOW dword): 0x07060302 ->
            // [b.hi16 | a.hi16<<16] = [bf16(s0), bf16(s1)] in memory order.
            uint2 d;
            d.x = __builtin_amdgcn_perm(u4[1], u4[0], 0x07060302u);
            d.y = __builtin_amdgcn_perm(u4[3], u4[2], 0x07060302u);
            *(uint2*)(&Hlds[e * HS + G * 8 + half * 4]) = d;
        }
        xv = xnext;
    }

    // ---- FC head: h (fp32) -> LDS, lanes 0..31 reduce 24 -> 2 ----
#pragma unroll
    for (int G = 0; G < 3; ++G) {
        float4 f4;
        f4.x = h[G * 4 + 0]; f4.y = h[G * 4 + 1];
        f4.z = h[G * 4 + 2]; f4.w = h[G * 4 + 3];
        *(float4*)(&Flds[e * FS + G * 8 + half * 4]) = f4;
    }
    if (lane < 32) {
        float o0 = fc_b[0], o1 = fc_b[1];
#pragma unroll
        for (int j = 0; j < 24; ++j) {
            const float hv = Flds[lane * FS + j];
            o0 = fmaf(hv, fc_w[j],      o0);
            o1 = fmaf(hv, fc_w[24 + j], o1);
        }
        float2 o; o.x = o0; o.y = o1;
        *(float2*)(out + (size_t)(elem0 + lane) * 2) = o;
    }
}

extern "C" void kernel_launch(void* const* d_in, const int* in_sizes, int n_in,
                              void* d_out, int out_size, void* d_ws, size_t ws_size,
                              hipStream_t stream) {
    const float* x    = (const float*)d_in[0];
    const float* W_ih = (const float*)d_in[1];
    const float* b_ih = (const float*)d_in[2];
    const float* W_hh = (const float*)d_in[3];
    const float* b_hh = (const float*)d_in[4];
    const float* fc_w = (const float*)d_in[5];
    const float* fc_b = (const float*)d_in[6];
    float* out = (float*)d_out;

    const int B = in_sizes[0] / GRU_T;      // 32768
    const int grid = B / 32;                // 1024 blocks x 1 wave
    trend_gru_mfma32<<<grid, 64, 0, stream>>>(x, W_ih, b_ih, W_hh, b_hh,
                                              fc_w, fc_b, out);
}